// Round 1
// baseline (479.511 us; speedup 1.0000x reference)
//
#include <hip/hip_runtime.h>
#include <math.h>

#define NC 200000
#define NT 2000
#define HH 256
#define NH_ 8
#define SCALE 0.17677669529663687f   // 32^-0.5
#define EPS 1e-5f

// ---------------- counting sort of cells by cluster ----------------

__global__ void k_hist(const int* __restrict__ labels, int* __restrict__ counts) {
  int i = blockIdx.x * 256 + threadIdx.x;
  if (i < NC) atomicAdd(&counts[labels[i]], 1);
}

__global__ void k_scan(const int* __restrict__ counts, int* __restrict__ offsets) {
  // single wave of 64 threads, 32 elements each (covers 2048 >= NT)
  int tid = threadIdx.x;
  int base = tid * 32;
  int local[32];
  int s = 0;
  #pragma unroll
  for (int k = 0; k < 32; k++) {
    int idx = base + k;
    int v = (idx < NT) ? counts[idx] : 0;
    local[k] = s;
    s += v;
  }
  int incl = s;
  #pragma unroll
  for (int d = 1; d < 64; d <<= 1) {
    int o = __shfl_up(incl, d, 64);
    if (tid >= d) incl += o;
  }
  int excl = incl - s;
  #pragma unroll
  for (int k = 0; k < 32; k++) {
    int idx = base + k;
    if (idx < NT) offsets[idx] = excl + local[k];
  }
  if (tid == 63) offsets[NT] = incl;   // == NC
}

__global__ void k_scatter(const int* __restrict__ labels, const int* __restrict__ offsets,
                          int* __restrict__ cursor, int* __restrict__ cindex) {
  int i = blockIdx.x * 256 + threadIdx.x;
  if (i < NC) {
    int c = labels[i];
    int pos = offsets[c] + atomicAdd(&cursor[c], 1);
    cindex[pos] = i;
  }
}

// ---------------- small GEMM: C[M,256] = A[M,256] @ W[256,256] + bias ----------------

__global__ __launch_bounds__(256) void k_gemm_bias(
    const float* __restrict__ A, const float* __restrict__ W,
    const float* __restrict__ bias, float* __restrict__ C, int M)
{
  __shared__ float Al[16][33];
  __shared__ float Wl[32][HH];
  int tid = threadIdx.x;
  int r0 = blockIdx.x * 16;
  float acc[16];
  #pragma unroll
  for (int r = 0; r < 16; r++) acc[r] = 0.f;
  for (int k0 = 0; k0 < HH; k0 += 32) {
    for (int e = tid; e < 16 * 32; e += 256) {
      int r = e >> 5, k = e & 31;
      int row = r0 + r;
      Al[r][k] = (row < M) ? A[(size_t)row * HH + k0 + k] : 0.f;
    }
    for (int e = tid; e < 32 * HH; e += 256) {
      int k = e >> 8, j = e & 255;
      Wl[k][j] = W[(size_t)(k0 + k) * HH + j];
    }
    __syncthreads();
    for (int k = 0; k < 32; k++) {
      float w = Wl[k][tid];
      #pragma unroll
      for (int r = 0; r < 16; r++) acc[r] += Al[r][k] * w;
    }
    __syncthreads();
  }
  float bj = bias[tid];
  #pragma unroll
  for (int r = 0; r < 16; r++) {
    int row = r0 + r;
    if (row < M) C[(size_t)row * HH + tid] = acc[r] + bj;
  }
}

// ---------------- Qproj[t,h,j] = SCALE * sum_d Wk[j,h*32+d] * Q[t,h*32+d] ----------------

__global__ __launch_bounds__(256) void k_qproj(
    const float* __restrict__ Q, const float* __restrict__ Wk, float* __restrict__ Qproj)
{
  __shared__ float Al[64][33];    // Q slice (SCALE folded in)
  __shared__ float Bl[32][257];   // Wk[j][h*32+d] transposed -> Bl[d][j]
  int h = blockIdx.x & 7, tb = blockIdx.x >> 3;
  int t0 = tb * 64;
  int tid = threadIdx.x;
  for (int e = tid; e < 64 * 32; e += 256) {
    int r = e >> 5, d = e & 31;
    int t = t0 + r;
    Al[r][d] = (t < NT) ? Q[(size_t)t * HH + h * 32 + d] * SCALE : 0.f;
  }
  for (int e = tid; e < 256 * 32; e += 256) {
    int j = e >> 5, d = e & 31;
    Bl[d][j] = Wk[(size_t)j * HH + h * 32 + d];
  }
  __syncthreads();
  float acc[64];
  #pragma unroll
  for (int r = 0; r < 64; r++) acc[r] = 0.f;
  for (int d = 0; d < 32; d++) {
    float b = Bl[d][tid];
    #pragma unroll
    for (int r = 0; r < 64; r++) acc[r] += Al[r][d] * b;
  }
  for (int r = 0; r < 64; r++) {
    int t = t0 + r;
    if (t < NT) Qproj[((size_t)t * NH_ + h) * HH + tid] = acc[r];
  }
}

__global__ void k_bkq(const float* __restrict__ Q, const float* __restrict__ bk,
                      float* __restrict__ bkq) {
  int g = blockIdx.x * 256 + threadIdx.x;   // g = t*8 + h
  if (g < NT * NH_) {
    int t = g >> 3, h = g & 7;
    float s = 0.f;
    #pragma unroll
    for (int d = 0; d < 32; d++) s += bk[h * 32 + d] * Q[(size_t)t * HH + h * 32 + d];
    bkq[g] = s * SCALE;
  }
}

// ---------------- main pass: per-tissue online-softmax weighted cell sum ----------------
// Block = 4 waves, one block per tissue. Wave processes one cell at a time:
// lane l holds cell row elements 4l..4l+3 and matching Qproj/Cw fragments in registers.

__global__ __launch_bounds__(256) void k_cellpass(
    const float* __restrict__ cell, const int* __restrict__ cindex,
    const int* __restrict__ offsets, const float* __restrict__ Qproj,
    const float* __restrict__ bkq, float* __restrict__ Cwn)
{
  int t = blockIdx.x;
  int n0 = offsets[t], n1 = offsets[t + 1];
  if (n1 == n0) return;
  int tid = threadIdx.x;
  int wave = tid >> 6, lane = tid & 63;

  float qp[NH_][4];
  #pragma unroll
  for (int h = 0; h < NH_; h++) {
    float4 v = *reinterpret_cast<const float4*>(&Qproj[((size_t)t * NH_ + h) * HH + lane * 4]);
    qp[h][0] = v.x; qp[h][1] = v.y; qp[h][2] = v.z; qp[h][3] = v.w;
  }
  float bq[NH_];
  #pragma unroll
  for (int h = 0; h < NH_; h++) bq[h] = bkq[t * NH_ + h];

  float m[NH_], dsum[NH_], cw[NH_][4];
  #pragma unroll
  for (int h = 0; h < NH_; h++) {
    m[h] = -1e30f; dsum[h] = 0.f;
    cw[h][0] = cw[h][1] = cw[h][2] = cw[h][3] = 0.f;
  }

  for (int i = n0 + wave; i < n1; i += 4) {
    int n = cindex[i];
    float4 x = *reinterpret_cast<const float4*>(&cell[(size_t)n * HH + lane * 4]);
    float p[NH_];
    #pragma unroll
    for (int h = 0; h < NH_; h++)
      p[h] = x.x * qp[h][0] + x.y * qp[h][1] + x.z * qp[h][2] + x.w * qp[h][3];
    #pragma unroll
    for (int d = 1; d < 64; d <<= 1) {
      #pragma unroll
      for (int h = 0; h < NH_; h++) p[h] += __shfl_xor(p[h], d, 64);
    }
    float s[NH_];
    bool need = false;
    #pragma unroll
    for (int h = 0; h < NH_; h++) { s[h] = p[h] + bq[h]; need = need || (s[h] > m[h]); }
    if (need) {           // wave-uniform branch (all lanes hold identical s,m)
      #pragma unroll
      for (int h = 0; h < NH_; h++) {
        float mn = fmaxf(m[h], s[h]);
        float sc = __expf(m[h] - mn);
        m[h] = mn;
        dsum[h] *= sc;
        cw[h][0] *= sc; cw[h][1] *= sc; cw[h][2] *= sc; cw[h][3] *= sc;
      }
    }
    #pragma unroll
    for (int h = 0; h < NH_; h++) {
      float e = __expf(s[h] - m[h]);
      dsum[h] += e;
      cw[h][0] += e * x.x; cw[h][1] += e * x.y; cw[h][2] += e * x.z; cw[h][3] += e * x.w;
    }
  }

  // merge the 4 per-wave partials (flash-style max merge)
  __shared__ float mlds[4][NH_];
  __shared__ float dlds[4][NH_];
  __shared__ float cwlds[NH_][HH];
  if (lane == 0) {
    #pragma unroll
    for (int h = 0; h < NH_; h++) { mlds[wave][h] = m[h]; dlds[wave][h] = dsum[h]; }
  }
  __syncthreads();
  float sw[NH_], dtot[NH_];
  #pragma unroll
  for (int h = 0; h < NH_; h++) {
    float g = fmaxf(fmaxf(mlds[0][h], mlds[1][h]), fmaxf(mlds[2][h], mlds[3][h]));
    sw[h] = __expf(m[h] - g);
    dtot[h] = dlds[0][h] * __expf(mlds[0][h] - g) + dlds[1][h] * __expf(mlds[1][h] - g)
            + dlds[2][h] * __expf(mlds[2][h] - g) + dlds[3][h] * __expf(mlds[3][h] - g);
  }
  if (wave == 0) {
    #pragma unroll
    for (int h = 0; h < NH_; h++) {
      cwlds[h][lane * 4 + 0] = cw[h][0] * sw[h];
      cwlds[h][lane * 4 + 1] = cw[h][1] * sw[h];
      cwlds[h][lane * 4 + 2] = cw[h][2] * sw[h];
      cwlds[h][lane * 4 + 3] = cw[h][3] * sw[h];
    }
  }
  __syncthreads();
  #pragma unroll
  for (int w = 1; w < 4; w++) {
    if (wave == w) {
      #pragma unroll
      for (int h = 0; h < NH_; h++) {
        cwlds[h][lane * 4 + 0] += cw[h][0] * sw[h];
        cwlds[h][lane * 4 + 1] += cw[h][1] * sw[h];
        cwlds[h][lane * 4 + 2] += cw[h][2] * sw[h];
        cwlds[h][lane * 4 + 3] += cw[h][3] * sw[h];
      }
    }
    __syncthreads();
  }
  // write normalized weighted cell-sum: Cwn[t,h,j] = (sum ex*cell)/denom
  #pragma unroll
  for (int h = 0; h < NH_; h++)
    Cwn[((size_t)t * NH_ + h) * HH + tid] = cwlds[h][tid] / dtot[h];
}

// ---------------- fused per-row tissue chain ----------------
// attended = Cwn @ Wv(+bv) per head -> @Wo_bu(+bo) -> select(counts>0) ->
// @Wv_td(+b) -> @Wo_td(+b) = td ; tissue_out = LN(tissue + tissue_updated)

#define TCH 8

__global__ __launch_bounds__(256) void k_tissuechain(
    const float* __restrict__ tissue, const int* __restrict__ counts,
    const float* __restrict__ Cwn,
    const float* __restrict__ Wv, const float* __restrict__ bv,
    const float* __restrict__ Wo, const float* __restrict__ bo,
    const float* __restrict__ Wvtd, const float* __restrict__ bvtd,
    const float* __restrict__ Wotd, const float* __restrict__ botd,
    const float* __restrict__ lng, const float* __restrict__ lnb,
    float* __restrict__ td, float* __restrict__ out_tissue)
{
  __shared__ float s_cwn[TCH][NH_ * HH];  // 64 KB
  __shared__ float s_a[TCH][HH];
  __shared__ float s_tu[TCH][HH];
  __shared__ float s_tmp[TCH][HH];
  __shared__ float s_red[2][4];
  int t0 = blockIdx.x * TCH;
  int j = threadIdx.x;
  int h = j >> 5;

  for (int e = j; e < TCH * NH_ * HH; e += 256)
    ((float*)s_cwn)[e] = Cwn[(size_t)t0 * NH_ * HH + e];
  __syncthreads();

  float acc[TCH];
  // attended (per-head GEMV against Wv columns)
  #pragma unroll
  for (int t = 0; t < TCH; t++) acc[t] = 0.f;
  for (int k = 0; k < HH; k++) {
    float w = Wv[(size_t)k * HH + j];
    #pragma unroll
    for (int t = 0; t < TCH; t++) acc[t] += s_cwn[t][h * HH + k] * w;
  }
  {
    float bj = bv[j];
    #pragma unroll
    for (int t = 0; t < TCH; t++) s_a[t][j] = acc[t] + bj;
  }
  __syncthreads();

  // out_bu = attended @ Wo_bu + bo ; select vs original tissue row
  #pragma unroll
  for (int t = 0; t < TCH; t++) acc[t] = 0.f;
  for (int k = 0; k < HH; k++) {
    float w = Wo[(size_t)k * HH + j];
    #pragma unroll
    for (int t = 0; t < TCH; t++) acc[t] += s_a[t][k] * w;
  }
  {
    float bj = bo[j];
    #pragma unroll
    for (int t = 0; t < TCH; t++) {
      int tt = t0 + t;
      s_tu[t][j] = (counts[tt] > 0) ? (acc[t] + bj) : tissue[(size_t)tt * HH + j];
    }
  }
  __syncthreads();

  // tmp = tu @ Wv_td + bv_td
  #pragma unroll
  for (int t = 0; t < TCH; t++) acc[t] = 0.f;
  for (int k = 0; k < HH; k++) {
    float w = Wvtd[(size_t)k * HH + j];
    #pragma unroll
    for (int t = 0; t < TCH; t++) acc[t] += s_tu[t][k] * w;
  }
  {
    float bj = bvtd[j];
    #pragma unroll
    for (int t = 0; t < TCH; t++) s_tmp[t][j] = acc[t] + bj;
  }
  __syncthreads();

  // td = tmp @ Wo_td + bo_td
  #pragma unroll
  for (int t = 0; t < TCH; t++) acc[t] = 0.f;
  for (int k = 0; k < HH; k++) {
    float w = Wotd[(size_t)k * HH + j];
    #pragma unroll
    for (int t = 0; t < TCH; t++) acc[t] += s_tmp[t][k] * w;
  }
  {
    float bj = botd[j];
    #pragma unroll
    for (int t = 0; t < TCH; t++) td[(size_t)(t0 + t) * HH + j] = acc[t] + bj;
  }

  // tissue_out = LayerNorm(tissue + tissue_updated)
  float gj = lng[j], bj2 = lnb[j];
  for (int t = 0; t < TCH; t++) {
    float y = tissue[(size_t)(t0 + t) * HH + j] + s_tu[t][j];
    float s1 = y, s2 = y * y;
    #pragma unroll
    for (int d = 1; d < 64; d <<= 1) { s1 += __shfl_xor(s1, d, 64); s2 += __shfl_xor(s2, d, 64); }
    int wv_ = j >> 6, ln_ = j & 63;
    __syncthreads();
    if (ln_ == 0) { s_red[0][wv_] = s1; s_red[1][wv_] = s2; }
    __syncthreads();
    s1 = s_red[0][0] + s_red[0][1] + s_red[0][2] + s_red[0][3];
    s2 = s_red[1][0] + s_red[1][1] + s_red[1][2] + s_red[1][3];
    float mean = s1 * (1.f / 256.f);
    float var = s2 * (1.f / 256.f) - mean * mean;
    float inv = rsqrtf(var + EPS);
    out_tissue[(size_t)(t0 + t) * HH + j] = (y - mean) * inv * gj + bj2;
  }
}

// ---------------- final: cell_out = LN(cell + td[label]) ----------------

__global__ __launch_bounds__(256) void k_cellout(
    const float* __restrict__ cell, const float* __restrict__ td,
    const int* __restrict__ labels,
    const float* __restrict__ lng, const float* __restrict__ lnb,
    float* __restrict__ out)
{
  int row = blockIdx.x * 4 + (threadIdx.x >> 6);
  if (row >= NC) return;
  int lane = threadIdx.x & 63;
  int c = labels[row];
  float4 x = *reinterpret_cast<const float4*>(&cell[(size_t)row * HH + lane * 4]);
  float4 u = *reinterpret_cast<const float4*>(&td[(size_t)c * HH + lane * 4]);
  float y0 = x.x + u.x, y1 = x.y + u.y, y2 = x.z + u.z, y3 = x.w + u.w;
  float s1 = y0 + y1 + y2 + y3;
  float s2 = y0 * y0 + y1 * y1 + y2 * y2 + y3 * y3;
  #pragma unroll
  for (int d = 1; d < 64; d <<= 1) { s1 += __shfl_xor(s1, d, 64); s2 += __shfl_xor(s2, d, 64); }
  float mean = s1 * (1.f / 256.f);
  float var = s2 * (1.f / 256.f) - mean * mean;
  float inv = rsqrtf(var + EPS);
  float4 g = *reinterpret_cast<const float4*>(&lng[lane * 4]);
  float4 b = *reinterpret_cast<const float4*>(&lnb[lane * 4]);
  float4 o;
  o.x = (y0 - mean) * inv * g.x + b.x;
  o.y = (y1 - mean) * inv * g.y + b.y;
  o.z = (y2 - mean) * inv * g.z + b.z;
  o.w = (y3 - mean) * inv * g.w + b.w;
  *reinterpret_cast<float4*>(&out[(size_t)row * HH + lane * 4]) = o;
}

// ---------------- launch ----------------

extern "C" void kernel_launch(void* const* d_in, const int* in_sizes, int n_in,
                              void* d_out, int out_size, void* d_ws, size_t ws_size,
                              hipStream_t stream) {
  const float* cell   = (const float*)d_in[0];
  const float* tissue = (const float*)d_in[1];
  const int*   labels = (const int*)d_in[2];
  // d_in[3] tissue_batch unused
  const float* Wq = (const float*)d_in[4];  const float* bq = (const float*)d_in[5];
  const float* Wk = (const float*)d_in[6];  const float* bk = (const float*)d_in[7];
  const float* Wv = (const float*)d_in[8];  const float* bv = (const float*)d_in[9];
  const float* Wo = (const float*)d_in[10]; const float* bo = (const float*)d_in[11];
  const float* Wvtd = (const float*)d_in[12]; const float* bvtd = (const float*)d_in[13];
  const float* Wotd = (const float*)d_in[14]; const float* botd = (const float*)d_in[15];
  const float* lncg = (const float*)d_in[16]; const float* lncb = (const float*)d_in[17];
  const float* lntg = (const float*)d_in[18]; const float* lntb = (const float*)d_in[19];
  float* out_cell   = (float*)d_out;
  float* out_tissue = (float*)d_out + (size_t)NC * HH;

  char* w = (char*)d_ws;
  auto take = [&](size_t bytes) { void* p = (void*)w; w += (bytes + 255) & ~(size_t)255; return p; };
  int*   counts  = (int*)take((size_t)NT * 4);          // zeroed below
  int*   cursor  = (int*)take((size_t)NT * 4);          // zeroed below (adjacent region)
  int*   offsets = (int*)take((size_t)(NT + 1) * 4);
  int*   cindex  = (int*)take((size_t)NC * 4);
  float* Q       = (float*)take((size_t)NT * HH * 4);
  float* Qproj   = (float*)take((size_t)NT * NH_ * HH * 4);
  float* bkq     = (float*)take((size_t)NT * NH_ * 4);
  float* Cwn     = (float*)take((size_t)NT * NH_ * HH * 4);
  float* td      = (float*)take((size_t)NT * HH * 4);

  // zero counts+cursor (they occupy the first 16384 bytes incl. padding)
  hipMemsetAsync(counts, 0, 16384, stream);

  const int CB = (NC + 255) / 256;   // 782
  k_hist<<<CB, 256, 0, stream>>>(labels, counts);
  k_scan<<<1, 64, 0, stream>>>(counts, offsets);
  k_scatter<<<CB, 256, 0, stream>>>(labels, offsets, cursor, cindex);

  k_gemm_bias<<<(NT + 15) / 16, 256, 0, stream>>>(tissue, Wq, bq, Q, NT);
  k_qproj<<<8 * ((NT + 63) / 64), 256, 0, stream>>>(Q, Wk, Qproj);
  k_bkq<<<(NT * NH_ + 255) / 256, 256, 0, stream>>>(Q, bk, bkq);

  k_cellpass<<<NT, 256, 0, stream>>>(cell, cindex, offsets, Qproj, bkq, Cwn);

  k_tissuechain<<<NT / TCH, 256, 0, stream>>>(tissue, counts, Cwn,
      Wv, bv, Wo, bo, Wvtd, bvtd, Wotd, botd, lntg, lntb, td, out_tissue);

  k_cellout<<<NC / 4, 256, 0, stream>>>(cell, td, labels, lncg, lncb, out_cell);
}